// Round 10
// baseline (68.828 us; speedup 1.0000x reference)
//
#include <hip/hip_runtime.h>
#include <hip/hip_bf16.h>

#define BB 4
#define SS 1024
#define NSD (BB*SS*64)

typedef __attribute__((ext_vector_type(4))) float f32x4;
typedef __attribute__((ext_vector_type(8))) short bf16x8;

__device__ __forceinline__ float fast_exp2(float x) { return __builtin_amdgcn_exp2f(x); }
__device__ __forceinline__ float fast_rcp(float x)  { return __builtin_amdgcn_rcpf(x); }

__device__ __forceinline__ unsigned short f2bf(float f) {
    unsigned int u = __builtin_bit_cast(unsigned int, f);
    u += 0x7fffu + ((u >> 16) & 1u);
    return (unsigned short)(u >> 16);
}
__device__ __forceinline__ float bf2f(unsigned short u) {
    unsigned int v = (unsigned int)u << 16;
    return __builtin_bit_cast(float, v);
}

// sum of 4 sigmoids 1/(1+eq_d*ek_d) with one reciprocal
__device__ __forceinline__ float sig4(const f32x4 eq, const f32x4 ek) {
    float A = __builtin_fmaf(eq[0], ek[0], 1.0f);
    float B = __builtin_fmaf(eq[1], ek[1], 1.0f);
    float C = __builtin_fmaf(eq[2], ek[2], 1.0f);
    float D = __builtin_fmaf(eq[3], ek[3], 1.0f);
    float AB = A*B, CD = C*D;
    float num = __builtin_fmaf(A+B, CD, (C+D)*AB);
    return num * fast_rcp(AB*CD);
}

// ---------------------------------------------------------------------------
// K1: projections + hi/lo bf16 splits (verified r4-r9; exfT4 dropped).
// ---------------------------------------------------------------------------
__global__ __launch_bounds__(256) void k_proj(
    const float* __restrict__ x, const float* __restrict__ Wq,
    const float* __restrict__ Wk, const float* __restrict__ bkv,
    const float* __restrict__ Wv,
    unsigned short* __restrict__ qh, unsigned short* __restrict__ ql,
    unsigned short* __restrict__ kh, unsigned short* __restrict__ kl,
    unsigned short* __restrict__ xh, unsigned short* __restrict__ xlo,
    float* __restrict__ exf,
    unsigned short* __restrict__ xT, unsigned short* __restrict__ vT)
{
    __shared__ float xsh[4*68];
    const int t = threadIdx.x;
    const int r = t & 3, cc = t >> 2;
    const int row0 = blockIdx.x * 4;
    if (t < 64) {
        const int rr = t >> 4, seg = (t & 15) * 4;
        *(f32x4*)(xsh + rr*68 + seg) =
            *(const f32x4*)(x + (size_t)(row0 + rr)*64 + seg);
    }
    __syncthreads();

    const float* wqp = Wq + cc*64;
    const float* wkp = Wk + cc*64;
    const float* wvp = Wv + cc*64;
    float aq = 0.f, ak = 0.f, av = 0.f;
    #pragma unroll 4
    for (int e0 = 0; e0 < 64; e0 += 4) {
        f32x4 xv = *(const f32x4*)(xsh + r*68 + e0);
        f32x4 q4 = *(const f32x4*)(wqp + e0);
        f32x4 k4 = *(const f32x4*)(wkp + e0);
        f32x4 v4 = *(const f32x4*)(wvp + e0);
        #pragma unroll
        for (int u = 0; u < 4; ++u) {
            aq = __builtin_fmaf(xv[u], q4[u], aq);
            ak = __builtin_fmaf(xv[u], k4[u], ak);
            av = __builtin_fmaf(xv[u], v4[u], av);
        }
    }
    const int row = row0 + r;
    const int b = row >> 10, srow = row & 1023;
    const float C2 = 2.8853900817779268f;   // 2*log2(e)
    ak += bkv[cc];
    const size_t idx = (size_t)row*64 + cc;
    unsigned short h;
    h = f2bf(aq); qh[idx] = h; ql[idx] = f2bf(aq - bf2f(h));
    h = f2bf(ak); kh[idx] = h; kl[idx] = f2bf(ak - bf2f(h));
    const float xv_ = xsh[r*68 + cc];
    h = f2bf(xv_); xh[idx] = h; xlo[idx] = f2bf(xv_ - bf2f(h));
    exf[idx] = fast_exp2(C2 * xv_);
    xT[((size_t)b*64 + cc)*1024 + srow] = h;
    vT[((size_t)b*64 + cc)*1024 + srow] = f2bf(av);
}

// ---------------------------------------------------------------------------
// K2a: branch 3. ONE WAVE = ONE 16q x 32k chunk-set job; zero barriers.
// Jobs: (b, qt, s) with s < m(qt)=min(16, qt/2+1); wave covers chunks
// c = s, s+16 (32k each). Total jobs = 4*784 = 3136 waves = 784 blocks
// (~3 blocks/CU at 54.3 KB LDS -> 3 waves/SIMD, single-pass residency).
// Per-wave LDS: eq[16][64] f32 + ek[32][64] f32, XOR-swizzled (quad m of
// row r stored at (m^(r&7))): per d-quad, 2 eq + 4 ek ds_read_b128 hit 8
// distinct bank-quads (8-lane broadcast) -> conflict-free.
// Lane tile: q = (l&7)+8i (i<2), k = (l>>3)+8j (j<4) -> 8 sig4 per d-quad.
// P -> per-wave LDS [16][40] bf16 -> MFMA A-frag; B from xT. Slots 4+s.
// ---------------------------------------------------------------------------
__global__ __launch_bounds__(256) void k_br3(
    const float* __restrict__ exf, const unsigned short* __restrict__ xT,
    float* __restrict__ po, float* __restrict__ lb)
{
    __shared__ float eqw_[4][16*64];
    __shared__ float ekw_[4][32*64];
    __shared__ unsigned short Plw_[4][16*40];
    const int t = threadIdx.x;
    const int lane = t & 63, wv = t >> 6;
    const int l7 = lane & 7, lk = lane >> 3;
    const int l15 = lane & 15, g = lane >> 4;

    // job decode: w -> (b, qt descending, s)
    const int w = blockIdx.x*4 + wv;
    const int b = w / 784;
    int j = w - b*784;
    int qt = 63;
    for (;;) {
        int m_ = (qt >> 1) + 1; if (m_ > 16) m_ = 16;
        if (j < m_) break;
        j -= m_; --qt;
    }
    const int s = j;
    const int q0 = qt * 16;
    const int nch = (qt >> 1) + 1;

    float* eqw = eqw_[wv];
    float* ekw = ekw_[wv];
    unsigned short* Plw = Plw_[wv];

    {   // stage eq 16x64 swizzled (per-wave; coalesced 1KB wave-loads)
        const float* src = exf + ((size_t)b*SS + q0)*64;
        #pragma unroll
        for (int ii = 0; ii < 4; ++ii) {
            const int idx = lane + 64*ii;
            const int r0 = idx >> 4, mq = idx & 15;
            *(f32x4*)(eqw + r0*64 + ((mq ^ (r0 & 7)) << 2)) =
                *(const f32x4*)(src + r0*64 + mq*4);
        }
    }

    const unsigned short* vb = xT + (size_t)b*64*1024;
    f32x4 acc[4];
    #pragma unroll
    for (int d = 0; d < 4; ++d) acc[d] = (f32x4){0.f,0.f,0.f,0.f};
    float lr0 = 0.f, lr1 = 0.f;

    for (int c = s; c < nch; c += 16) {
        const int kc = c * 32;
        {   // stage ek 32x64 swizzled (per-wave; same-wave reuse is safe)
            const float* src = exf + ((size_t)b*SS + kc)*64;
            #pragma unroll
            for (int ii = 0; ii < 8; ++ii) {
                const int idx = lane + 64*ii;
                const int r0 = idx >> 4, mq = idx & 15;
                *(f32x4*)(ekw + r0*64 + ((mq ^ (r0 & 7)) << 2)) =
                    *(const f32x4*)(src + r0*64 + mq*4);
            }
        }
        float ar[2][4] = {};
        #pragma unroll 4
        for (int m = 0; m < 16; ++m) {
            f32x4 eqv0 = *(const f32x4*)(eqw + l7*64       + ((m ^ l7) << 2));
            f32x4 eqv1 = *(const f32x4*)(eqw + (l7+8)*64   + ((m ^ l7) << 2));
            f32x4 ekv[4];
            #pragma unroll
            for (int jj = 0; jj < 4; ++jj)
                ekv[jj] = *(const f32x4*)(ekw + (lk + 8*jj)*64 + ((m ^ lk) << 2));
            #pragma unroll
            for (int jj = 0; jj < 4; ++jj) {
                ar[0][jj] += sig4(eqv0, ekv[jj]);
                ar[1][jj] += sig4(eqv1, ekv[jj]);
            }
        }
        // p = e^{s3-32}, s3 = 64-2ar -> exp2(fma(ar,-2log2e, 32log2e)); mask
        #pragma unroll
        for (int i = 0; i < 2; ++i) {
            const int q = q0 + l7 + 8*i;
            #pragma unroll
            for (int jj = 0; jj < 4; ++jj) {
                const int k = kc + lk + 8*jj;
                float e = (k <= q)
                    ? fast_exp2(__builtin_fmaf(ar[i][jj], -2.8853900817779268f,
                                               46.166241308446475f))
                    : 0.f;
                if (i == 0) lr0 += e; else lr1 += e;
                Plw[(l7 + 8*i)*40 + lk + 8*jj] = f2bf(e);
            }
        }
        // PV: one A-frag (k=32) + 4 d-blocks of B from xT
        bf16x8 af = *(const bf16x8*)(Plw + l15*40 + g*8);
        #pragma unroll
        for (int db = 0; db < 4; ++db) {
            bf16x8 bf_ = *(const bf16x8*)(vb + (size_t)(db*16 + l15)*1024 + kc + g*8);
            acc[db] = __builtin_amdgcn_mfma_f32_16x16x32_bf16(af, bf_, acc[db], 0, 0, 0);
        }
    }
    // row sums: reduce over the 8 lanes sharing l&7 (stride-8 xor ladder)
    lr0 += __shfl_xor(lr0, 8, 64);  lr1 += __shfl_xor(lr1, 8, 64);
    lr0 += __shfl_xor(lr0, 16, 64); lr1 += __shfl_xor(lr1, 16, 64);
    lr0 += __shfl_xor(lr0, 32, 64); lr1 += __shfl_xor(lr1, 32, 64);

    const size_t slot = 4 + s;
    if (lane < 8) {
        lb[slot*(size_t)(BB*SS) + (size_t)b*SS + q0 + lane]     = lr0;
        lb[slot*(size_t)(BB*SS) + (size_t)b*SS + q0 + 8 + lane] = lr1;
    }
    float* pob = po + slot*(size_t)NSD + ((size_t)b*SS + q0)*64;
    #pragma unroll
    for (int i = 0; i < 4; ++i) {
        const int rr = g*4 + i;
        #pragma unroll
        for (int db = 0; db < 4; ++db)
            pob[(size_t)rr*64 + db*16 + l15] = acc[db][i];
    }
}

// ---------------------------------------------------------------------------
// K2b: branches 1,2 (split-bf16 MFMA scores) — r9-verified standalone kernel.
// 1024 blocks x 256. Slots 0..3.
// ---------------------------------------------------------------------------
__global__ __launch_bounds__(256) void k_br12(
    const unsigned short* __restrict__ xh, const unsigned short* __restrict__ xlo,
    const unsigned short* __restrict__ qh, const unsigned short* __restrict__ ql,
    const unsigned short* __restrict__ kh, const unsigned short* __restrict__ kl,
    const unsigned short* __restrict__ xT, const unsigned short* __restrict__ vT,
    const float* __restrict__ attn_scale,
    float* __restrict__ po, float* __restrict__ lb)
{
    __shared__ unsigned short Pl[16*72];
    __shared__ float lpart[4][16];
    const int t = threadIdx.x;
    const int lane = t & 63, wv = t >> 6;
    const int l15 = lane & 15, g = lane >> 4;
    const float LOG2E = 1.4426950408889634f;

    const int y = blockIdx.x;
    const int split = y & 1, b = (y >> 1) & 3;
    const int qt = 63 - ((y >> 3) & 63);
    const int br = (y >> 9) & 1;
    const int q0 = qt * 16;
    const int nc = (qt >> 2) + 1;

    const unsigned short* Ah_p = (br ? qh : xh) + ((size_t)b*SS + q0)*64;
    const unsigned short* Al_p = (br ? ql : xlo) + ((size_t)b*SS + q0)*64;
    const unsigned short* Bh_p = (br ? kh : xh) + (size_t)b*SS*64;
    const unsigned short* Bl_p = (br ? kl : xlo) + (size_t)b*SS*64;
    const unsigned short* Vb   = (br ? vT : xT) + (size_t)b*64*1024;

    const int ko = g * 8;
    bf16x8 Ah0 = *(const bf16x8*)(Ah_p + (size_t)l15*64 + ko);
    bf16x8 Ah1 = *(const bf16x8*)(Ah_p + (size_t)l15*64 + 32 + ko);
    bf16x8 Al0 = *(const bf16x8*)(Al_p + (size_t)l15*64 + ko);
    bf16x8 Al1 = *(const bf16x8*)(Al_p + (size_t)l15*64 + 32 + ko);

    const float pscale = br ? (0.125f * attn_scale[0] * LOG2E) : LOG2E;
    const float pshift = br ? 0.f : (-64.f * LOG2E);

    f32x4 lacc = {0,0,0,0};
    f32x4 oacc = {0,0,0,0};

    for (int c = split; c < nc; c += 2) {
        const int kc = c * 64;
        const int krow = kc + wv*16 + l15;
        bf16x8 Bh0 = *(const bf16x8*)(Bh_p + (size_t)krow*64 + ko);
        bf16x8 Bh1 = *(const bf16x8*)(Bh_p + (size_t)krow*64 + 32 + ko);
        bf16x8 Bl0 = *(const bf16x8*)(Bl_p + (size_t)krow*64 + ko);
        bf16x8 Bl1 = *(const bf16x8*)(Bl_p + (size_t)krow*64 + 32 + ko);
        f32x4 s = {0,0,0,0};
        s = __builtin_amdgcn_mfma_f32_16x16x32_bf16(Ah0, Bh0, s, 0, 0, 0);
        s = __builtin_amdgcn_mfma_f32_16x16x32_bf16(Ah1, Bh1, s, 0, 0, 0);
        s = __builtin_amdgcn_mfma_f32_16x16x32_bf16(Ah0, Bl0, s, 0, 0, 0);
        s = __builtin_amdgcn_mfma_f32_16x16x32_bf16(Ah1, Bl1, s, 0, 0, 0);
        s = __builtin_amdgcn_mfma_f32_16x16x32_bf16(Al0, Bh0, s, 0, 0, 0);
        s = __builtin_amdgcn_mfma_f32_16x16x32_bf16(Al1, Bh1, s, 0, 0, 0);
        const int kg = kc + wv*16 + l15;
        #pragma unroll
        for (int i = 0; i < 4; ++i) {
            const int q = q0 + g*4 + i;
            float e = (kg <= q) ? fast_exp2(__builtin_fmaf(s[i], pscale, pshift)) : 0.f;
            lacc[i] += e;
            Pl[(g*4+i)*72 + wv*16 + l15] = f2bf(e);
        }
        __syncthreads();
        #pragma unroll
        for (int ks = 0; ks < 2; ++ks) {
            bf16x8 af = *(const bf16x8*)(Pl + l15*72 + ks*32 + g*8);
            bf16x8 bf_ = *(const bf16x8*)(Vb + (size_t)(wv*16 + l15)*1024 + kc + ks*32 + g*8);
            oacc = __builtin_amdgcn_mfma_f32_16x16x32_bf16(af, bf_, oacc, 0, 0, 0);
        }
        __syncthreads();
    }
    #pragma unroll
    for (int off = 8; off >= 1; off >>= 1) {
        lacc[0] += __shfl_xor(lacc[0], off, 64);
        lacc[1] += __shfl_xor(lacc[1], off, 64);
        lacc[2] += __shfl_xor(lacc[2], off, 64);
        lacc[3] += __shfl_xor(lacc[3], off, 64);
    }
    if (l15 == 0) {
        #pragma unroll
        for (int i = 0; i < 4; ++i) lpart[wv][g*4 + i] = lacc[i];
    }
    __syncthreads();
    const size_t slot = (size_t)(br*2 + split);
    if (t < 16) {
        float l = lpart[0][t] + lpart[1][t] + lpart[2][t] + lpart[3][t];
        lb[slot*((size_t)BB*SS) + (size_t)b*SS + q0 + t] = l;
    }
    float* pob = po + slot*((size_t)NSD) + ((size_t)b*SS + q0)*64;
    #pragma unroll
    for (int i = 0; i < 4; ++i)
        pob[(size_t)(g*4 + i)*64 + wv*16 + l15] = oacc[i];
}

// ---------------------------------------------------------------------------
// K3: out = w0*(p0+p1)/(l0+l1) + w1*(p2+p3)/(l2+l3) + w2*(br3 slots s < ns)
// ns per row = min(16, qt/2+1), qt = 16-row tile index (32k-chunk slots).
// ---------------------------------------------------------------------------
__global__ __launch_bounds__(256) void k_comb(
    const float* __restrict__ po, const float* __restrict__ lb,
    const float* __restrict__ attn_w, float* __restrict__ out)
{
    const int v = blockIdx.x*256 + threadIdx.x;      // f32x4 index over [B,S,D]
    const int qg = v >> 4;                           // global row b*S+q
    const int qt = (qg & 1023) >> 4;
    int ns = (qt >> 1) + 1; if (ns > 16) ns = 16;
    const float aw0 = attn_w[0], aw1 = attn_w[1], aw2 = attn_w[2];
    const float iws = fast_rcp(aw0 + aw1 + aw2);
    const f32x4* p = (const f32x4*)po;
    const int NQ = BB*SS;

    f32x4 s01 = p[(size_t)0*65536 + v] + p[(size_t)1*65536 + v];
    f32x4 s23 = p[(size_t)2*65536 + v] + p[(size_t)3*65536 + v];
    f32x4 s3s = {0,0,0,0};
    float l3 = 0.f;
    #pragma unroll
    for (int s = 0; s < 16; ++s) {
        if (s < ns) {
            s3s += p[(size_t)(4+s)*65536 + v];
            l3 += lb[(4+s)*NQ + qg];
        }
    }
    const float f0 = aw0 * iws * fast_rcp(lb[0*NQ + qg] + lb[1*NQ + qg]);
    const float f1 = aw1 * iws * fast_rcp(lb[2*NQ + qg] + lb[3*NQ + qg]);
    const float f2 = aw2 * iws * fast_rcp(l3);
    f32x4 o;
    #pragma unroll
    for (int u = 0; u < 4; ++u)
        o[u] = __builtin_fmaf(s01[u], f0,
               __builtin_fmaf(s23[u], f1, s3s[u]*f2));
    ((f32x4*)out)[v] = o;
}

extern "C" void kernel_launch(void* const* d_in, const int* in_sizes, int n_in,
                              void* d_out, int out_size, void* d_ws, size_t ws_size,
                              hipStream_t stream) {
    (void)in_sizes; (void)n_in; (void)out_size; (void)ws_size;
    const float* x          = (const float*)d_in[0];
    const float* Wq         = (const float*)d_in[1];
    const float* Wk         = (const float*)d_in[2];
    const float* bk         = (const float*)d_in[3];
    const float* Wv         = (const float*)d_in[4];
    const float* attn_w     = (const float*)d_in[5];
    const float* attn_scale = (const float*)d_in[6];
    float* out              = (float*)d_out;

    // workspace carve-up (~27 MB; ws is ~268 MB)
    float* exf = (float*)d_ws;                            // [B,S,64] f32
    unsigned short* qh  = (unsigned short*)(exf + NSD);   // 6 bf16 [B,S,64]
    unsigned short* ql  = qh  + NSD;
    unsigned short* kh  = ql  + NSD;
    unsigned short* kl  = kh  + NSD;
    unsigned short* xh  = kl  + NSD;
    unsigned short* xlo = xh  + NSD;
    unsigned short* xT  = xlo + NSD;                      // bf16 [B,64,S]
    unsigned short* vT  = xT  + NSD;
    float* po = (float*)(vT + NSD);                       // [20][B,S,64] f32
    float* lb = po + (size_t)20*NSD;                      // [20][B*S]

    k_proj <<<1024, 256, 0, stream>>>(x, Wq, Wk, bk, Wv,
                                      qh, ql, kh, kl, xh, xlo, exf, xT, vT);
    k_br3  <<<784, 256, 0, stream>>>(exf, xT, po, lb);
    k_br12 <<<1024, 256, 0, stream>>>(xh, xlo, qh, ql, kh, kl, xT, vT,
                                      attn_scale, po, lb);
    k_comb <<<256, 256, 0, stream>>>(po, lb, attn_w, out);
}